// Round 6
// baseline (124.606 us; speedup 1.0000x reference)
//
#include <hip/hip_runtime.h>

#define NPTS 32768

typedef _Float16 f16;
typedef _Float16 f16x2 __attribute__((ext_vector_type(2)));
typedef _Float16 f16x8 __attribute__((ext_vector_type(8)));
typedef float f32x2 __attribute__((ext_vector_type(2)));
typedef float f32x4 __attribute__((ext_vector_type(4)));
typedef unsigned int u32x4 __attribute__((ext_vector_type(4)));

union U16 { u32x4 u; f32x4 f; f16x2 h2[4]; f16x8 h8; };

static __device__ __forceinline__ f16x2 pk_fma(f16x2 a, f16x2 b, f16x2 c) {
  return __builtin_elementwise_fma(a, b, c);
}
static __device__ __forceinline__ f16x2 pk_relu(f16x2 a) {
  f16x2 z = {(f16)0.f, (f16)0.f};
  return __builtin_elementwise_max(a, z);
}
static __device__ __forceinline__ f16x2 pk_cvt(float a, float b) {
  return __builtin_bit_cast(f16x2, __builtin_amdgcn_cvt_pkrtz(a, b));
}
// volatile LDS read: forbids LICM so per-pass streamed weights are truly
// re-read each pass (transient regs), not hoisted into resident registers.
static __device__ __forceinline__ u32x4 lds_stream(const u32x4* p) {
  return *(const volatile u32x4*)p;
}

// Per used-gas (gi = 0..73): composition index (h2o nets 7,8 unused downstream).
__device__ const unsigned char G_T[74] = {
  0,0,0,0,0,0,0, 0,0,0,0,0,0,0,0,0,0,0,0,0,0,0,0,0,0,0,0,
  1,1,1,1,1,1,1,1,1,1,1,1,1,
  2,2,2,2,2,2,2,2,2,
  3,3,3,
  4,4,4,4,4,4,4,4,4,
  5,5,5,5,5,5,5,5,5,5,5,5,5
};

// Channel gather tables: for each of the 29 output channels, up to 6 source
// gas planes (gi indices; 255 = unused).
__device__ const unsigned char CH_SRC[29][6] = {
  { 0,27,40,49,52,61}, { 1,28,41,50,53,62}, { 2,29,42,51,54,63},
  { 3,55,255,255,255,255}, { 4,56,255,255,255,255},
  { 5,43,255,255,255,255}, { 6,44,255,255,255,255},
  { 3,57,255,255,255,255}, { 4,58,255,255,255,255},
  { 7,45,255,255,255,255}, { 8,46,255,255,255,255},
  { 9,59,255,255,255,255}, {10,60,255,255,255,255},
  {11,47,255,255,255,255}, {12,48,255,255,255,255},
  {13,64,255,255,255,255}, {14,65,255,255,255,255},
  {15,30,66,255,255,255}, {16,31,67,255,255,255}, {17,32,68,255,255,255},
  {18,33,69,255,255,255}, {19,34,70,255,255,255}, {20,35,71,255,255,255},
  {21,255,255,255,255,255}, {22,255,255,255,255,255},
  {23,36,255,255,255,255}, {24,37,255,255,255,255},
  {25,38,72,255,255,255}, {26,39,73,255,255,255}
};
__device__ const unsigned char CH_CNT[29] = {
  6,6,6, 2,2,2,2,2,2,2,2,2,2,2,2,2,2, 3,3,3,3,3,3, 1,1, 2,2, 3,3
};

// Packed-weight layout in d_ws: uint4 slots, addr = ((gi*22 + slot)*64 + lane).
// slots 0-7: W2 A-fragments (mt*2+ks); 8-9: W1 row0; 10-11: W1 row1;
// 12-13: b1; 14-17: b2; 18-21: Wout.
#define NSLOT 22
#define PACK_SLOTS (74 * NSLOT * 64)

// ---------------------------------------------------------------------------
// k0w: repack weights into fragment-ready lane order. 74 blocks x 64 threads.
// ---------------------------------------------------------------------------
__global__ __launch_bounds__(64) void k0w_pack(
    const float* __restrict__ W1, const float* __restrict__ b1,
    const float* __restrict__ W2, const float* __restrict__ b2,
    const float* __restrict__ Wout, u32x4* __restrict__ pack)
{
  const int gi   = blockIdx.x;
  const int lane = threadIdx.x;
  const int l15  = lane & 15;
  const int quad = lane >> 4;
  const int g    = gi + (gi >= 7 ? 2 : 0);

  const float* W2g = W2 + g * 4096;
  const float* W1g = W1 + g * 128;
  const float* b1g = b1 + g * 64;
  u32x4* dst = pack + gi * NSLOT * 64 + lane;

  #pragma unroll
  for (int mt = 0; mt < 4; ++mt)
    #pragma unroll
    for (int ks = 0; ks < 2; ++ks) {
      U16 u;
      #pragma unroll
      for (int j = 0; j < 4; ++j) {
        const float* s = W2g + (ks * 32 + quad * 8 + 2 * j) * 64 + mt * 16 + l15;
        u.h2[j] = pk_cvt(s[0], s[64]);
      }
      dst[(mt * 2 + ks) * 64] = u.u;
    }
  #pragma unroll
  for (int ks = 0; ks < 2; ++ks) {
    U16 a, b, c;
    #pragma unroll
    for (int j = 0; j < 4; ++j) {
      int h = ks * 32 + quad * 8 + 2 * j;
      a.h2[j] = pk_cvt(W1g[h],      W1g[h + 1]);
      b.h2[j] = pk_cvt(W1g[64 + h], W1g[64 + h + 1]);
      c.h2[j] = pk_cvt(b1g[h],      b1g[h + 1]);
    }
    dst[(8 + ks) * 64]  = a.u;
    dst[(10 + ks) * 64] = b.u;
    dst[(12 + ks) * 64] = c.u;
  }
  #pragma unroll
  for (int mt = 0; mt < 4; ++mt) {
    U16 u, v;
    u.f = *(const f32x4*)(b2   + g * 64 + mt * 16 + quad * 4);
    v.f = *(const f32x4*)(Wout + g * 64 + mt * 16 + quad * 4);
    dst[(14 + mt) * 64] = u.u;
    dst[(18 + mt) * 64] = v.u;
  }
}

// ---------------------------------------------------------------------------
// k1: per-gas MLP (2->64->64->1) -> private per-gas plane.
// R6: REAL register streaming.  R2-R5 post-mortem: the per-pass LDS weight
// reads are loop-invariant, so the compiler could LICM-hoist them back into
// resident registers -- which explains why every source-level register cut
// left residency at ~2.3 blocks/CU (2 waves/SIMD band, >128 live regs), and
// why forced bounds spilled instead (scratch allocation also caps residency).
// Changes:
//   * layer-1 weights (w0/w1/b1) now ALSO staged in LDS (18 slots, 18.4 KB);
//   * all per-pass streamed LDS reads are VOLATILE -> no hoisting; weights
//     are transient per pass.  Peak live ~100 regs -> 4 waves/SIMD.
//   * (256,2): no forced register split, no spill path.
// ---------------------------------------------------------------------------
__global__ __launch_bounds__(256, 2) void k1_mlp(
    const float* __restrict__ t_p, const float* __restrict__ comp,
    const u32x4* __restrict__ pack, const float* __restrict__ bout,
    float* __restrict__ planes)
{
  // 18 slots: 0-7 W2 afrags, 8-11 b2 (glob 14-17), 12-13 W1r0 (glob 8-9),
  // 14-15 W1r1 (glob 10-11), 16-17 b1 (glob 12-13).  18432 B.
  __shared__ u32x4 wlds[18 * 64];

  const int tid  = threadIdx.x;
  const int lane = tid & 63;
  const int l15  = lane & 15;
  const int quad = lane >> 4;
  const int wid  = tid >> 6;
  const int w    = blockIdx.x * 4 + wid;
  const int gi   = w >> 7;                 // 128 waves per gas; uniform per block
  const int g    = gi + (gi >= 7 ? 2 : 0);
  const int pb0  = (w & 127) * 256;
  const int t    = G_T[gi];

  const u32x4* psrc = pack + gi * (NSLOT * 64);

  // ---- stage streamed slots to LDS (shared by the block's 4 waves)
  #pragma unroll
  for (int s = wid; s < 18; s += 4) {
    const int gs = s < 8 ? s : (s < 12 ? s + 6 : s - 4);
    wlds[s * 64 + lane] = psrc[gs * 64 + lane];
  }

  // ---- resident-only: Wout + bias (9 regs) + input prefetch
  const u32x4* pksrc = psrc + lane;
  f32x2 wq2[4][2];
  #pragma unroll
  for (int mt = 0; mt < 4; ++mt) {
    f32x4 wv = __builtin_bit_cast(f32x4, pksrc[(18 + mt) * 64]);
    wq2[mt][0] = f32x2{ wv[0], wv[1] };
    wq2[mt][1] = f32x2{ wv[2], wv[3] };
  }
  const float bo = bout[g];

  __syncthreads();

  const float2* tp2  = (const float2*)t_p;
  const float* compt = comp + t * NPTS;
  float* plane = planes + gi * NPTS;

  const bool qb0 = (quad & 1) != 0;
  const bool qb1 = (quad & 2) != 0;

  // ---- prefetch pass 0 inputs (64 points per pass)
  float2 xv_n[4];
  float cv_n;
  #pragma unroll
  for (int pt = 0; pt < 4; ++pt)
    xv_n[pt] = tp2[pb0 + pt * 16 + l15];
  cv_n = compt[pb0 + lane];

  #pragma unroll
  for (int pass = 0; pass < 4; ++pass) {
    const int pb = pb0 + pass * 64;

    // consume the prefetch BEFORE overwriting it (no xv copy regs)
    f16x2 x0v[4], x1v[4];
    #pragma unroll
    for (int pt = 0; pt < 4; ++pt) {
      x0v[pt] = pk_cvt(xv_n[pt].x, xv_n[pt].x);
      x1v[pt] = pk_cvt(xv_n[pt].y, xv_n[pt].y);
    }
    const float cv = cv_n;

    // issue next pass's loads
    if (pass < 3) {
      const int pbn = pb + 64;
      #pragma unroll
      for (int pt = 0; pt < 4; ++pt)
        xv_n[pt] = tp2[pbn + pt * 16 + l15];
      cv_n = compt[pbn + lane];
    }

    // layer 1: weights streamed (volatile) from LDS, transient per pass
    U16 bfrag[2][4];
    #pragma unroll
    for (int ks = 0; ks < 2; ++ks) {
      U16 w0s, w1s, b1s;
      w0s.u = lds_stream(&wlds[(12 + ks) * 64 + lane]);
      w1s.u = lds_stream(&wlds[(14 + ks) * 64 + lane]);
      b1s.u = lds_stream(&wlds[(16 + ks) * 64 + lane]);
      #pragma unroll
      for (int pt = 0; pt < 4; ++pt)
        #pragma unroll
        for (int i = 0; i < 4; ++i)
          bfrag[ks][pt].h2[i] =
              pk_relu(pk_fma(x0v[pt], w0s.h2[i],
                             pk_fma(x1v[pt], w1s.h2[i], b1s.h2[i])));
    }

    // layer 2 (afrag/b2 streamed volatile from LDS) + per-mt layer-3 fold
    f32x2 p2[4];
    #pragma unroll
    for (int pt = 0; pt < 4; ++pt) p2[pt] = f32x2{ 0.f, 0.f };

    #pragma unroll
    for (int mt = 0; mt < 4; ++mt) {
      const f16x8 af0 = __builtin_bit_cast(f16x8, lds_stream(&wlds[(mt * 2 + 0) * 64 + lane]));
      const f16x8 af1 = __builtin_bit_cast(f16x8, lds_stream(&wlds[(mt * 2 + 1) * 64 + lane]));
      const f32x4 bq  = __builtin_bit_cast(f32x4, lds_stream(&wlds[(8 + mt) * 64 + lane]));

      f32x4 c[4];
      #pragma unroll
      for (int pt = 0; pt < 4; ++pt)
        c[pt] = __builtin_amdgcn_mfma_f32_16x16x32_f16(af0, bfrag[0][pt].h8, bq, 0, 0, 0);
      #pragma unroll
      for (int pt = 0; pt < 4; ++pt)
        c[pt] = __builtin_amdgcn_mfma_f32_16x16x32_f16(af1, bfrag[1][pt].h8, c[pt], 0, 0, 0);

      #pragma unroll
      for (int pt = 0; pt < 4; ++pt) {
        const f32x2 z = { 0.f, 0.f };
        f32x2 a0 = __builtin_elementwise_max(f32x2{ c[pt][0], c[pt][1] }, z);
        f32x2 a1 = __builtin_elementwise_max(f32x2{ c[pt][2], c[pt][3] }, z);
        p2[pt] = __builtin_elementwise_fma(a0, wq2[mt][0], p2[pt]);
        p2[pt] = __builtin_elementwise_fma(a1, wq2[mt][1], p2[pt]);
      }
    }

    float p[4];
    #pragma unroll
    for (int pt = 0; pt < 4; ++pt) p[pt] = p2[pt][0] + p2[pt][1];

    // quad transpose-reduce: 3 shuffles, 4 results (one per quad) -- all 64
    // lanes finish with one point each (R0-verified mapping).
    float u  = qb1 ? (qb0 ? p[3] : p[2]) : (qb0 ? p[1] : p[0]);
    float v  = qb1 ? (qb0 ? p[2] : p[3]) : (qb0 ? p[0] : p[1]);
    float w2 = qb1 ? (qb0 ? p[1] : p[0]) : (qb0 ? p[3] : p[2]);
    float x  = qb1 ? (qb0 ? p[0] : p[1]) : (qb0 ? p[2] : p[3]);
    float s  = u + __shfl_xor(v, 16, 64);
    float tt = w2 + __shfl_xor(x, 16, 64);
    float r  = s + __shfl_xor(tt, 32, 64);

    const float tau = fmaxf(r + bo, 0.f) * cv;
    plane[pb + lane] = tau;   // 256B coalesced store, all lanes
  }
}

// ---------------------------------------------------------------------------
// k2: gather planes -> 29 channels (fan-in 1..6, wave-uniform), and produce
// tau_lw / tau_iw.  Pure BW: ~21 MB total.
// ---------------------------------------------------------------------------
__global__ __launch_bounds__(256) void k2_gather(
    const float* __restrict__ planes, const float* __restrict__ comp,
    const float* __restrict__ ke_lw, const float* __restrict__ ke_iw,
    float* __restrict__ out)
{
  const int c  = blockIdx.x >> 5;                               // 0..28
  const int n  = (((blockIdx.x & 31) << 8) + threadIdx.x) * 4;  // point base

  const int cnt = CH_CNT[c];
  f32x4 acc = *(const f32x4*)(planes + (int)CH_SRC[c][0] * NPTS + n);
  for (int j = 1; j < cnt; ++j)                                 // wave-uniform trip
    acc += *(const f32x4*)(planes + (int)CH_SRC[c][j] * NPTS + n);
  *(f32x4*)(out + c * NPTS + n) = acc;

  f32x4 c6 = *(const f32x4*)(comp + 6 * NPTS + n);
  f32x4 c7 = *(const f32x4*)(comp + 7 * NPTS + n);
  *(f32x4*)(out + (29 + c) * NPTS + n) = c6 * ke_lw[c];
  *(f32x4*)(out + (58 + c) * NPTS + n) = c7 * ke_iw[c];
}

// ---------------------------------------------------------------------------
extern "C" void kernel_launch(void* const* d_in, const int* in_sizes, int n_in,
                              void* d_out, int out_size, void* d_ws, size_t ws_size,
                              hipStream_t stream)
{
  const float* t_p   = (const float*)d_in[0];
  const float* comp  = (const float*)d_in[1];
  const float* W1    = (const float*)d_in[2];
  const float* b1    = (const float*)d_in[3];
  const float* W2    = (const float*)d_in[4];
  const float* b2    = (const float*)d_in[5];
  const float* Wout  = (const float*)d_in[6];
  const float* bout  = (const float*)d_in[7];
  const float* ke_lw = (const float*)d_in[8];
  const float* ke_iw = (const float*)d_in[9];
  float* out = (float*)d_out;

  u32x4* pack   = (u32x4*)d_ws;                 // 74*22*64*16 B = 1.63 MB
  float* planes = (float*)(pack + PACK_SLOTS);  // 74*32768*4 B  = 9.70 MB

  k0w_pack<<<74, 64, 0, stream>>>(W1, b1, W2, b2, Wout, pack);
  k1_mlp<<<2368, 256, 0, stream>>>(t_p, comp, pack, bout, planes);
  k2_gather<<<29 * 32, 256, 0, stream>>>(planes, comp, ke_lw, ke_iw, out);
}

// Round 7
// 117.129 us; speedup vs baseline: 1.0638x; 1.0638x over previous
//
#include <hip/hip_runtime.h>

#define NPTS 32768

typedef _Float16 f16;
typedef _Float16 f16x2 __attribute__((ext_vector_type(2)));
typedef _Float16 f16x8 __attribute__((ext_vector_type(8)));
typedef float f32x2 __attribute__((ext_vector_type(2)));
typedef float f32x4 __attribute__((ext_vector_type(4)));
typedef unsigned int u32x4 __attribute__((ext_vector_type(4)));

union U16 { u32x4 u; f32x4 f; f16x2 h2[4]; f16x8 h8; };

static __device__ __forceinline__ f16x2 pk_fma(f16x2 a, f16x2 b, f16x2 c) {
  return __builtin_elementwise_fma(a, b, c);
}
static __device__ __forceinline__ f16x2 pk_relu(f16x2 a) {
  f16x2 z = {(f16)0.f, (f16)0.f};
  return __builtin_elementwise_max(a, z);
}
static __device__ __forceinline__ f16x2 pk_cvt(float a, float b) {
  return __builtin_bit_cast(f16x2, __builtin_amdgcn_cvt_pkrtz(a, b));
}

// Per used-gas (gi = 0..73): composition index (h2o nets 7,8 unused downstream).
__device__ const unsigned char G_T[74] = {
  0,0,0,0,0,0,0, 0,0,0,0,0,0,0,0,0,0,0,0,0,0,0,0,0,0,0,0,
  1,1,1,1,1,1,1,1,1,1,1,1,1,
  2,2,2,2,2,2,2,2,2,
  3,3,3,
  4,4,4,4,4,4,4,4,4,
  5,5,5,5,5,5,5,5,5,5,5,5,5
};

// Channel gather tables: for each of the 29 output channels, up to 6 source
// gas planes (gi indices; 255 = unused).
__device__ const unsigned char CH_SRC[29][6] = {
  { 0,27,40,49,52,61}, { 1,28,41,50,53,62}, { 2,29,42,51,54,63},
  { 3,55,255,255,255,255}, { 4,56,255,255,255,255},
  { 5,43,255,255,255,255}, { 6,44,255,255,255,255},
  { 3,57,255,255,255,255}, { 4,58,255,255,255,255},
  { 7,45,255,255,255,255}, { 8,46,255,255,255,255},
  { 9,59,255,255,255,255}, {10,60,255,255,255,255},
  {11,47,255,255,255,255}, {12,48,255,255,255,255},
  {13,64,255,255,255,255}, {14,65,255,255,255,255},
  {15,30,66,255,255,255}, {16,31,67,255,255,255}, {17,32,68,255,255,255},
  {18,33,69,255,255,255}, {19,34,70,255,255,255}, {20,35,71,255,255,255},
  {21,255,255,255,255,255}, {22,255,255,255,255,255},
  {23,36,255,255,255,255}, {24,37,255,255,255,255},
  {25,38,72,255,255,255}, {26,39,73,255,255,255}
};
__device__ const unsigned char CH_CNT[29] = {
  6,6,6, 2,2,2,2,2,2,2,2,2,2,2,2,2,2, 3,3,3,3,3,3, 1,1, 2,2, 3,3
};

// Packed-weight layout in d_ws: uint4 slots, addr = ((gi*22 + slot)*64 + lane).
// slots 0-7: W2 A-fragments (mt*2+ks); 8-9: W1 row0; 10-11: W1 row1;
// 12-13: b1; 14-17: b2; 18-21: Wout.
#define NSLOT 22
#define PACK_SLOTS (74 * NSLOT * 64)

// ---------------------------------------------------------------------------
// k0w: repack weights into fragment-ready lane order. 74 blocks x 64 threads.
// ---------------------------------------------------------------------------
__global__ __launch_bounds__(64) void k0w_pack(
    const float* __restrict__ W1, const float* __restrict__ b1,
    const float* __restrict__ W2, const float* __restrict__ b2,
    const float* __restrict__ Wout, u32x4* __restrict__ pack)
{
  const int gi   = blockIdx.x;
  const int lane = threadIdx.x;
  const int l15  = lane & 15;
  const int quad = lane >> 4;
  const int g    = gi + (gi >= 7 ? 2 : 0);

  const float* W2g = W2 + g * 4096;
  const float* W1g = W1 + g * 128;
  const float* b1g = b1 + g * 64;
  u32x4* dst = pack + gi * NSLOT * 64 + lane;

  #pragma unroll
  for (int mt = 0; mt < 4; ++mt)
    #pragma unroll
    for (int ks = 0; ks < 2; ++ks) {
      U16 u;
      #pragma unroll
      for (int j = 0; j < 4; ++j) {
        const float* s = W2g + (ks * 32 + quad * 8 + 2 * j) * 64 + mt * 16 + l15;
        u.h2[j] = pk_cvt(s[0], s[64]);
      }
      dst[(mt * 2 + ks) * 64] = u.u;
    }
  #pragma unroll
  for (int ks = 0; ks < 2; ++ks) {
    U16 a, b, c;
    #pragma unroll
    for (int j = 0; j < 4; ++j) {
      int h = ks * 32 + quad * 8 + 2 * j;
      a.h2[j] = pk_cvt(W1g[h],      W1g[h + 1]);
      b.h2[j] = pk_cvt(W1g[64 + h], W1g[64 + h + 1]);
      c.h2[j] = pk_cvt(b1g[h],      b1g[h + 1]);
    }
    dst[(8 + ks) * 64]  = a.u;
    dst[(10 + ks) * 64] = b.u;
    dst[(12 + ks) * 64] = c.u;
  }
  #pragma unroll
  for (int mt = 0; mt < 4; ++mt) {
    U16 u, v;
    u.f = *(const f32x4*)(b2   + g * 64 + mt * 16 + quad * 4);
    v.f = *(const f32x4*)(Wout + g * 64 + mt * 16 + quad * 4);
    dst[(14 + mt) * 64] = u.u;
    dst[(18 + mt) * 64] = v.u;
  }
}

// ---------------------------------------------------------------------------
// k1: per-gas MLP (2->64->64->1) -> private per-gas plane.
// R7: BLOCK-SIZE EXPERIMENT.  R1-R6 post-mortem: occupancy is pinned at
// 19-29% (~2 blocks of 4 waves per CU) regardless of VGPR (64-88), LDS
// (0-22.5 KB), grid (1184/2368), and bounds -- i.e. quantized per BLOCK,
// not per wave-resource.  Two candidate caps: (a) per-wave arch+AGPR
// allocation >128 -> hard 2 waves/SIMD; (b) a ~2-blocks/CU slot limit.
// Same per-wave code at 512 threads (8 waves/block) separates them:
// if (b), waves/CU doubles; if (a), occupancy stays ~25% and R8 targets
// total regs <= 128.  Structure otherwise = R5 exact (best measured:
// non-volatile reads, 12-slot LDS stage, w0/w1/b1 resident, pt=4,
// no spill; R6's volatile cost 3 us -> reverted).
// ---------------------------------------------------------------------------
__global__ __launch_bounds__(512, 2) void k1_mlp(
    const float* __restrict__ t_p, const float* __restrict__ comp,
    const u32x4* __restrict__ pack, const float* __restrict__ bout,
    float* __restrict__ planes)
{
  __shared__ u32x4 wlds[12 * 64];   // 12288 B: slots 0-7 = W2 afrags, 8-11 = b2

  const int tid  = threadIdx.x;
  const int lane = tid & 63;
  const int l15  = lane & 15;
  const int quad = lane >> 4;
  const int wid  = tid >> 6;               // 0..7
  const int w    = blockIdx.x * 8 + wid;
  const int gi   = w >> 7;                 // 128 waves per gas; uniform per block
  const int g    = gi + (gi >= 7 ? 2 : 0);
  const int pb0  = (w & 127) * 256;
  const int t    = G_T[gi];

  const u32x4* psrc = pack + gi * (NSLOT * 64);

  // ---- stage streamed slots to LDS (shared by the block's 8 waves)
  #pragma unroll
  for (int s = wid; s < 12; s += 8) {
    const int gs = s < 8 ? s : s + 6;      // local 8-11 <- global 14-17 (b2)
    wlds[s * 64 + lane] = psrc[gs * 64 + lane];
  }

  // ---- once-per-wave weights straight from global (L2-resident)
  const u32x4* pksrc = psrc + lane;
  U16 w0s[2], w1s[2], b1s[2];
  #pragma unroll
  for (int ks = 0; ks < 2; ++ks) {
    w0s[ks].u = pksrc[(8 + ks) * 64];
    w1s[ks].u = pksrc[(10 + ks) * 64];
    b1s[ks].u = pksrc[(12 + ks) * 64];
  }
  f32x2 wq2[4][2];
  #pragma unroll
  for (int mt = 0; mt < 4; ++mt) {
    f32x4 wv = __builtin_bit_cast(f32x4, pksrc[(18 + mt) * 64]);
    wq2[mt][0] = f32x2{ wv[0], wv[1] };
    wq2[mt][1] = f32x2{ wv[2], wv[3] };
  }
  const float bo = bout[g];

  __syncthreads();

  const float2* tp2  = (const float2*)t_p;
  const float* compt = comp + t * NPTS;
  float* plane = planes + gi * NPTS;

  const bool qb0 = (quad & 1) != 0;
  const bool qb1 = (quad & 2) != 0;

  // ---- prefetch pass 0 inputs (64 points per pass)
  float2 xv_n[4];
  float cv_n;
  #pragma unroll
  for (int pt = 0; pt < 4; ++pt)
    xv_n[pt] = tp2[pb0 + pt * 16 + l15];
  cv_n = compt[pb0 + lane];

  #pragma unroll
  for (int pass = 0; pass < 4; ++pass) {
    const int pb = pb0 + pass * 64;

    float2 xv[4];
    #pragma unroll
    for (int pt = 0; pt < 4; ++pt) xv[pt] = xv_n[pt];
    const float cv = cv_n;

    // issue next pass's loads before this pass's compute
    if (pass < 3) {
      const int pbn = pb + 64;
      #pragma unroll
      for (int pt = 0; pt < 4; ++pt)
        xv_n[pt] = tp2[pbn + pt * 16 + l15];
      cv_n = compt[pbn + lane];
    }

    f16x2 x0v[4], x1v[4];
    #pragma unroll
    for (int pt = 0; pt < 4; ++pt) {
      x0v[pt] = pk_cvt(xv[pt].x, xv[pt].x);
      x1v[pt] = pk_cvt(xv[pt].y, xv[pt].y);
    }

    // layer 1 -> B fragments (k = ks*32 + quad*8 + j-pair)
    U16 bfrag[2][4];
    #pragma unroll
    for (int ks = 0; ks < 2; ++ks)
      #pragma unroll
      for (int pt = 0; pt < 4; ++pt)
        #pragma unroll
        for (int i = 0; i < 4; ++i)
          bfrag[ks][pt].h2[i] =
              pk_relu(pk_fma(x0v[pt], w0s[ks].h2[i],
                             pk_fma(x1v[pt], w1s[ks].h2[i], b1s[ks].h2[i])));

    // layer 2 (afrag/b2 streamed from LDS) + per-mt layer-3 fold
    f32x2 p2[4];
    #pragma unroll
    for (int pt = 0; pt < 4; ++pt) p2[pt] = f32x2{ 0.f, 0.f };

    #pragma unroll
    for (int mt = 0; mt < 4; ++mt) {
      const f16x8 af0 = __builtin_bit_cast(f16x8, wlds[(mt * 2 + 0) * 64 + lane]);
      const f16x8 af1 = __builtin_bit_cast(f16x8, wlds[(mt * 2 + 1) * 64 + lane]);
      const f32x4 bq  = __builtin_bit_cast(f32x4, wlds[(8 + mt) * 64 + lane]);

      f32x4 c[4];
      #pragma unroll
      for (int pt = 0; pt < 4; ++pt)
        c[pt] = __builtin_amdgcn_mfma_f32_16x16x32_f16(af0, bfrag[0][pt].h8, bq, 0, 0, 0);
      #pragma unroll
      for (int pt = 0; pt < 4; ++pt)
        c[pt] = __builtin_amdgcn_mfma_f32_16x16x32_f16(af1, bfrag[1][pt].h8, c[pt], 0, 0, 0);

      #pragma unroll
      for (int pt = 0; pt < 4; ++pt) {
        const f32x2 z = { 0.f, 0.f };
        f32x2 a0 = __builtin_elementwise_max(f32x2{ c[pt][0], c[pt][1] }, z);
        f32x2 a1 = __builtin_elementwise_max(f32x2{ c[pt][2], c[pt][3] }, z);
        p2[pt] = __builtin_elementwise_fma(a0, wq2[mt][0], p2[pt]);
        p2[pt] = __builtin_elementwise_fma(a1, wq2[mt][1], p2[pt]);
      }
    }

    float p[4];
    #pragma unroll
    for (int pt = 0; pt < 4; ++pt) p[pt] = p2[pt][0] + p2[pt][1];

    // quad transpose-reduce: 3 shuffles, 4 results (one per quad) -- all 64
    // lanes finish with one point each (R0-verified mapping).
    float u  = qb1 ? (qb0 ? p[3] : p[2]) : (qb0 ? p[1] : p[0]);
    float v  = qb1 ? (qb0 ? p[2] : p[3]) : (qb0 ? p[0] : p[1]);
    float w2 = qb1 ? (qb0 ? p[1] : p[0]) : (qb0 ? p[3] : p[2]);
    float x  = qb1 ? (qb0 ? p[0] : p[1]) : (qb0 ? p[2] : p[3]);
    float s  = u + __shfl_xor(v, 16, 64);
    float tt = w2 + __shfl_xor(x, 16, 64);
    float r  = s + __shfl_xor(tt, 32, 64);

    const float tau = fmaxf(r + bo, 0.f) * cv;
    plane[pb + lane] = tau;   // 256B coalesced store, all lanes
  }
}

// ---------------------------------------------------------------------------
// k2: gather planes -> 29 channels (fan-in 1..6, wave-uniform), and produce
// tau_lw / tau_iw.  Pure BW: ~21 MB total.
// ---------------------------------------------------------------------------
__global__ __launch_bounds__(256) void k2_gather(
    const float* __restrict__ planes, const float* __restrict__ comp,
    const float* __restrict__ ke_lw, const float* __restrict__ ke_iw,
    float* __restrict__ out)
{
  const int c  = blockIdx.x >> 5;                               // 0..28
  const int n  = (((blockIdx.x & 31) << 8) + threadIdx.x) * 4;  // point base

  const int cnt = CH_CNT[c];
  f32x4 acc = *(const f32x4*)(planes + (int)CH_SRC[c][0] * NPTS + n);
  for (int j = 1; j < cnt; ++j)                                 // wave-uniform trip
    acc += *(const f32x4*)(planes + (int)CH_SRC[c][j] * NPTS + n);
  *(f32x4*)(out + c * NPTS + n) = acc;

  f32x4 c6 = *(const f32x4*)(comp + 6 * NPTS + n);
  f32x4 c7 = *(const f32x4*)(comp + 7 * NPTS + n);
  *(f32x4*)(out + (29 + c) * NPTS + n) = c6 * ke_lw[c];
  *(f32x4*)(out + (58 + c) * NPTS + n) = c7 * ke_iw[c];
}

// ---------------------------------------------------------------------------
extern "C" void kernel_launch(void* const* d_in, const int* in_sizes, int n_in,
                              void* d_out, int out_size, void* d_ws, size_t ws_size,
                              hipStream_t stream)
{
  const float* t_p   = (const float*)d_in[0];
  const float* comp  = (const float*)d_in[1];
  const float* W1    = (const float*)d_in[2];
  const float* b1    = (const float*)d_in[3];
  const float* W2    = (const float*)d_in[4];
  const float* b2    = (const float*)d_in[5];
  const float* Wout  = (const float*)d_in[6];
  const float* bout  = (const float*)d_in[7];
  const float* ke_lw = (const float*)d_in[8];
  const float* ke_iw = (const float*)d_in[9];
  float* out = (float*)d_out;

  u32x4* pack   = (u32x4*)d_ws;                 // 74*22*64*16 B = 1.63 MB
  float* planes = (float*)(pack + PACK_SLOTS);  // 74*32768*4 B  = 9.70 MB

  k0w_pack<<<74, 64, 0, stream>>>(W1, b1, W2, b2, Wout, pack);
  k1_mlp<<<1184, 512, 0, stream>>>(t_p, comp, pack, bout, planes);
  k2_gather<<<29 * 32, 256, 0, stream>>>(planes, comp, ke_lw, ke_iw, out);
}

// Round 8
// 114.811 us; speedup vs baseline: 1.0853x; 1.0202x over previous
//
#include <hip/hip_runtime.h>

#define NPTS 32768

typedef _Float16 f16;
typedef _Float16 f16x2 __attribute__((ext_vector_type(2)));
typedef _Float16 f16x8 __attribute__((ext_vector_type(8)));
typedef float f32x2 __attribute__((ext_vector_type(2)));
typedef float f32x4 __attribute__((ext_vector_type(4)));
typedef unsigned int u32x4 __attribute__((ext_vector_type(4)));

union U16 { u32x4 u; f32x4 f; f16x2 h2[4]; f16x8 h8; };

static __device__ __forceinline__ f16x2 pk_fma(f16x2 a, f16x2 b, f16x2 c) {
  return __builtin_elementwise_fma(a, b, c);
}
static __device__ __forceinline__ f16x2 pk_relu(f16x2 a) {
  f16x2 z = {(f16)0.f, (f16)0.f};
  return __builtin_elementwise_max(a, z);
}
static __device__ __forceinline__ f16x2 pk_cvt(float a, float b) {
  return __builtin_bit_cast(f16x2, __builtin_amdgcn_cvt_pkrtz(a, b));
}

// Per used-gas (gi = 0..73): composition index (h2o nets 7,8 unused downstream).
__device__ const unsigned char G_T[74] = {
  0,0,0,0,0,0,0, 0,0,0,0,0,0,0,0,0,0,0,0,0,0,0,0,0,0,0,0,
  1,1,1,1,1,1,1,1,1,1,1,1,1,
  2,2,2,2,2,2,2,2,2,
  3,3,3,
  4,4,4,4,4,4,4,4,4,
  5,5,5,5,5,5,5,5,5,5,5,5,5
};

// Channel gather tables: for each of the 29 output channels, up to 6 source
// gas planes (gi indices; 255 = unused).
__device__ const unsigned char CH_SRC[29][6] = {
  { 0,27,40,49,52,61}, { 1,28,41,50,53,62}, { 2,29,42,51,54,63},
  { 3,55,255,255,255,255}, { 4,56,255,255,255,255},
  { 5,43,255,255,255,255}, { 6,44,255,255,255,255},
  { 3,57,255,255,255,255}, { 4,58,255,255,255,255},
  { 7,45,255,255,255,255}, { 8,46,255,255,255,255},
  { 9,59,255,255,255,255}, {10,60,255,255,255,255},
  {11,47,255,255,255,255}, {12,48,255,255,255,255},
  {13,64,255,255,255,255}, {14,65,255,255,255,255},
  {15,30,66,255,255,255}, {16,31,67,255,255,255}, {17,32,68,255,255,255},
  {18,33,69,255,255,255}, {19,34,70,255,255,255}, {20,35,71,255,255,255},
  {21,255,255,255,255,255}, {22,255,255,255,255,255},
  {23,36,255,255,255,255}, {24,37,255,255,255,255},
  {25,38,72,255,255,255}, {26,39,73,255,255,255}
};
__device__ const unsigned char CH_CNT[29] = {
  6,6,6, 2,2,2,2,2,2,2,2,2,2,2,2,2,2, 3,3,3,3,3,3, 1,1, 2,2, 3,3
};

// Packed-weight layout in d_ws: uint4 slots, addr = ((gi*22 + slot)*64 + lane).
// slots 0-7: W2 A-fragments (mt*2+ks); 8-9: W1 row0; 10-11: W1 row1;
// 12-13: b1; 14-17: b2; 18-21: Wout.
#define NSLOT 22
#define PACK_SLOTS (74 * NSLOT * 64)

// ---------------------------------------------------------------------------
// k0w: repack weights into fragment-ready lane order. 74 blocks x 64 threads.
// ---------------------------------------------------------------------------
__global__ __launch_bounds__(64) void k0w_pack(
    const float* __restrict__ W1, const float* __restrict__ b1,
    const float* __restrict__ W2, const float* __restrict__ b2,
    const float* __restrict__ Wout, u32x4* __restrict__ pack)
{
  const int gi   = blockIdx.x;
  const int lane = threadIdx.x;
  const int l15  = lane & 15;
  const int quad = lane >> 4;
  const int g    = gi + (gi >= 7 ? 2 : 0);

  const float* W2g = W2 + g * 4096;
  const float* W1g = W1 + g * 128;
  const float* b1g = b1 + g * 64;
  u32x4* dst = pack + gi * NSLOT * 64 + lane;

  #pragma unroll
  for (int mt = 0; mt < 4; ++mt)
    #pragma unroll
    for (int ks = 0; ks < 2; ++ks) {
      U16 u;
      #pragma unroll
      for (int j = 0; j < 4; ++j) {
        const float* s = W2g + (ks * 32 + quad * 8 + 2 * j) * 64 + mt * 16 + l15;
        u.h2[j] = pk_cvt(s[0], s[64]);
      }
      dst[(mt * 2 + ks) * 64] = u.u;
    }
  #pragma unroll
  for (int ks = 0; ks < 2; ++ks) {
    U16 a, b, c;
    #pragma unroll
    for (int j = 0; j < 4; ++j) {
      int h = ks * 32 + quad * 8 + 2 * j;
      a.h2[j] = pk_cvt(W1g[h],      W1g[h + 1]);
      b.h2[j] = pk_cvt(W1g[64 + h], W1g[64 + h + 1]);
      c.h2[j] = pk_cvt(b1g[h],      b1g[h + 1]);
    }
    dst[(8 + ks) * 64]  = a.u;
    dst[(10 + ks) * 64] = b.u;
    dst[(12 + ks) * 64] = c.u;
  }
  #pragma unroll
  for (int mt = 0; mt < 4; ++mt) {
    U16 u, v;
    u.f = *(const f32x4*)(b2   + g * 64 + mt * 16 + quad * 4);
    v.f = *(const f32x4*)(Wout + g * 64 + mt * 16 + quad * 4);
    dst[(14 + mt) * 64] = u.u;
    dst[(18 + mt) * 64] = v.u;
  }
}

// ---------------------------------------------------------------------------
// k1: per-gas MLP (2->64->64->1) -> private per-gas plane.
// R8: GRID SCALING AT CONSTANT CHAIN COUNT.  The 7-round record:
//   * blocks/CU is the only axis with measured un-flattened positive slope
//     (R1->R3: 4.6->9.25 blk/CU = -16%; chain-halving R3->R4 only -8%).
//   * VALU instruction count sets a ~20 us floor (650 instr/wave-pass x
//     37.9k passes / 1024 SIMDs); measured VALUBusy 43% -> ~2x available
//     from issue rate alone.
//   * VGPR 84 permits ~6 blocks/CU; LDS 12.3KB permits 13 -> headroom.
// Change vs R5 (best): 4736 blocks x 4 waves (18.5 offered blocks/CU),
// 256 waves/gas, 128 pts/wave = 2 passes x 64 pts.  Chain count unchanged
// at the best-measured 37.9k.  If k1 doesn't move, the ~2-blocks/CU cap is
// hard and the structure is at its latency-bound ceiling.
// ---------------------------------------------------------------------------
__global__ __launch_bounds__(256, 2) void k1_mlp(
    const float* __restrict__ t_p, const float* __restrict__ comp,
    const u32x4* __restrict__ pack, const float* __restrict__ bout,
    float* __restrict__ planes)
{
  __shared__ u32x4 wlds[12 * 64];   // 12288 B: slots 0-7 = W2 afrags, 8-11 = b2

  const int tid  = threadIdx.x;
  const int lane = tid & 63;
  const int l15  = lane & 15;
  const int quad = lane >> 4;
  const int wid  = tid >> 6;
  const int w    = blockIdx.x * 4 + wid;
  const int gi   = w >> 8;                 // 256 waves per gas; uniform per block
  const int g    = gi + (gi >= 7 ? 2 : 0);
  const int pb0  = (w & 255) * 128;
  const int t    = G_T[gi];

  const u32x4* psrc = pack + gi * (NSLOT * 64);

  // ---- stage streamed slots to LDS (shared by the block's 4 waves)
  #pragma unroll
  for (int s = wid; s < 12; s += 4) {
    const int gs = s < 8 ? s : s + 6;      // local 8-11 <- global 14-17 (b2)
    wlds[s * 64 + lane] = psrc[gs * 64 + lane];
  }

  // ---- once-per-wave weights straight from global (L2-resident)
  const u32x4* pksrc = psrc + lane;
  U16 w0s[2], w1s[2], b1s[2];
  #pragma unroll
  for (int ks = 0; ks < 2; ++ks) {
    w0s[ks].u = pksrc[(8 + ks) * 64];
    w1s[ks].u = pksrc[(10 + ks) * 64];
    b1s[ks].u = pksrc[(12 + ks) * 64];
  }
  f32x2 wq2[4][2];
  #pragma unroll
  for (int mt = 0; mt < 4; ++mt) {
    f32x4 wv = __builtin_bit_cast(f32x4, pksrc[(18 + mt) * 64]);
    wq2[mt][0] = f32x2{ wv[0], wv[1] };
    wq2[mt][1] = f32x2{ wv[2], wv[3] };
  }
  const float bo = bout[g];

  __syncthreads();

  const float2* tp2  = (const float2*)t_p;
  const float* compt = comp + t * NPTS;
  float* plane = planes + gi * NPTS;

  const bool qb0 = (quad & 1) != 0;
  const bool qb1 = (quad & 2) != 0;

  // ---- prefetch pass 0 inputs (64 points per pass)
  float2 xv_n[4];
  float cv_n;
  #pragma unroll
  for (int pt = 0; pt < 4; ++pt)
    xv_n[pt] = tp2[pb0 + pt * 16 + l15];
  cv_n = compt[pb0 + lane];

  #pragma unroll
  for (int pass = 0; pass < 2; ++pass) {
    const int pb = pb0 + pass * 64;

    float2 xv[4];
    #pragma unroll
    for (int pt = 0; pt < 4; ++pt) xv[pt] = xv_n[pt];
    const float cv = cv_n;

    // issue next pass's loads before this pass's compute
    if (pass < 1) {
      const int pbn = pb + 64;
      #pragma unroll
      for (int pt = 0; pt < 4; ++pt)
        xv_n[pt] = tp2[pbn + pt * 16 + l15];
      cv_n = compt[pbn + lane];
    }

    f16x2 x0v[4], x1v[4];
    #pragma unroll
    for (int pt = 0; pt < 4; ++pt) {
      x0v[pt] = pk_cvt(xv[pt].x, xv[pt].x);
      x1v[pt] = pk_cvt(xv[pt].y, xv[pt].y);
    }

    // layer 1 -> B fragments (k = ks*32 + quad*8 + j-pair)
    U16 bfrag[2][4];
    #pragma unroll
    for (int ks = 0; ks < 2; ++ks)
      #pragma unroll
      for (int pt = 0; pt < 4; ++pt)
        #pragma unroll
        for (int i = 0; i < 4; ++i)
          bfrag[ks][pt].h2[i] =
              pk_relu(pk_fma(x0v[pt], w0s[ks].h2[i],
                             pk_fma(x1v[pt], w1s[ks].h2[i], b1s[ks].h2[i])));

    // layer 2 (afrag/b2 streamed from LDS) + per-mt layer-3 fold
    f32x2 p2[4];
    #pragma unroll
    for (int pt = 0; pt < 4; ++pt) p2[pt] = f32x2{ 0.f, 0.f };

    #pragma unroll
    for (int mt = 0; mt < 4; ++mt) {
      const f16x8 af0 = __builtin_bit_cast(f16x8, wlds[(mt * 2 + 0) * 64 + lane]);
      const f16x8 af1 = __builtin_bit_cast(f16x8, wlds[(mt * 2 + 1) * 64 + lane]);
      const f32x4 bq  = __builtin_bit_cast(f32x4, wlds[(8 + mt) * 64 + lane]);

      f32x4 c[4];
      #pragma unroll
      for (int pt = 0; pt < 4; ++pt)
        c[pt] = __builtin_amdgcn_mfma_f32_16x16x32_f16(af0, bfrag[0][pt].h8, bq, 0, 0, 0);
      #pragma unroll
      for (int pt = 0; pt < 4; ++pt)
        c[pt] = __builtin_amdgcn_mfma_f32_16x16x32_f16(af1, bfrag[1][pt].h8, c[pt], 0, 0, 0);

      #pragma unroll
      for (int pt = 0; pt < 4; ++pt) {
        const f32x2 z = { 0.f, 0.f };
        f32x2 a0 = __builtin_elementwise_max(f32x2{ c[pt][0], c[pt][1] }, z);
        f32x2 a1 = __builtin_elementwise_max(f32x2{ c[pt][2], c[pt][3] }, z);
        p2[pt] = __builtin_elementwise_fma(a0, wq2[mt][0], p2[pt]);
        p2[pt] = __builtin_elementwise_fma(a1, wq2[mt][1], p2[pt]);
      }
    }

    float p[4];
    #pragma unroll
    for (int pt = 0; pt < 4; ++pt) p[pt] = p2[pt][0] + p2[pt][1];

    // quad transpose-reduce: 3 shuffles, 4 results (one per quad) -- all 64
    // lanes finish with one point each (R0-verified mapping).
    float u  = qb1 ? (qb0 ? p[3] : p[2]) : (qb0 ? p[1] : p[0]);
    float v  = qb1 ? (qb0 ? p[2] : p[3]) : (qb0 ? p[0] : p[1]);
    float w2 = qb1 ? (qb0 ? p[1] : p[0]) : (qb0 ? p[3] : p[2]);
    float x  = qb1 ? (qb0 ? p[0] : p[1]) : (qb0 ? p[2] : p[3]);
    float s  = u + __shfl_xor(v, 16, 64);
    float tt = w2 + __shfl_xor(x, 16, 64);
    float r  = s + __shfl_xor(tt, 32, 64);

    const float tau = fmaxf(r + bo, 0.f) * cv;
    plane[pb + lane] = tau;   // 256B coalesced store, all lanes
  }
}

// ---------------------------------------------------------------------------
// k2: gather planes -> 29 channels (fan-in 1..6, wave-uniform), and produce
// tau_lw / tau_iw.  Pure BW: ~21 MB total.
// ---------------------------------------------------------------------------
__global__ __launch_bounds__(256) void k2_gather(
    const float* __restrict__ planes, const float* __restrict__ comp,
    const float* __restrict__ ke_lw, const float* __restrict__ ke_iw,
    float* __restrict__ out)
{
  const int c  = blockIdx.x >> 5;                               // 0..28
  const int n  = (((blockIdx.x & 31) << 8) + threadIdx.x) * 4;  // point base

  const int cnt = CH_CNT[c];
  f32x4 acc = *(const f32x4*)(planes + (int)CH_SRC[c][0] * NPTS + n);
  for (int j = 1; j < cnt; ++j)                                 // wave-uniform trip
    acc += *(const f32x4*)(planes + (int)CH_SRC[c][j] * NPTS + n);
  *(f32x4*)(out + c * NPTS + n) = acc;

  f32x4 c6 = *(const f32x4*)(comp + 6 * NPTS + n);
  f32x4 c7 = *(const f32x4*)(comp + 7 * NPTS + n);
  *(f32x4*)(out + (29 + c) * NPTS + n) = c6 * ke_lw[c];
  *(f32x4*)(out + (58 + c) * NPTS + n) = c7 * ke_iw[c];
}

// ---------------------------------------------------------------------------
extern "C" void kernel_launch(void* const* d_in, const int* in_sizes, int n_in,
                              void* d_out, int out_size, void* d_ws, size_t ws_size,
                              hipStream_t stream)
{
  const float* t_p   = (const float*)d_in[0];
  const float* comp  = (const float*)d_in[1];
  const float* W1    = (const float*)d_in[2];
  const float* b1    = (const float*)d_in[3];
  const float* W2    = (const float*)d_in[4];
  const float* b2    = (const float*)d_in[5];
  const float* Wout  = (const float*)d_in[6];
  const float* bout  = (const float*)d_in[7];
  const float* ke_lw = (const float*)d_in[8];
  const float* ke_iw = (const float*)d_in[9];
  float* out = (float*)d_out;

  u32x4* pack   = (u32x4*)d_ws;                 // 74*22*64*16 B = 1.63 MB
  float* planes = (float*)(pack + PACK_SLOTS);  // 74*32768*4 B  = 9.70 MB

  k0w_pack<<<74, 64, 0, stream>>>(W1, b1, W2, b2, Wout, pack);
  k1_mlp<<<4736, 256, 0, stream>>>(t_p, comp, pack, bout, planes);
  k2_gather<<<29 * 32, 256, 0, stream>>>(planes, comp, ke_lw, ke_iw, out);
}